// Round 11
// baseline (1368.999 us; speedup 1.0000x reference)
//
#include <hip/hip_runtime.h>
#include <hip/hip_bf16.h>
#include <stdint.h>

typedef __attribute__((ext_vector_type(8))) short bf16x8;
typedef __attribute__((ext_vector_type(4))) float f32x4;

#define MFMA16(a, b, c) __builtin_amdgcn_mfma_f32_16x16x32_bf16((a), (b), (c), 0, 0, 0)

// raw barrier: drain own LDS ops, then s_barrier. NO vmcnt drain -> global
// prefetch loads stay in flight across the barrier.
#define BARRIER_LGKM() do { \
  asm volatile("s_waitcnt lgkmcnt(0)" ::: "memory"); \
  __builtin_amdgcn_sched_barrier(0); \
  __builtin_amdgcn_s_barrier(); \
  __builtin_amdgcn_sched_barrier(0); } while (0)

static __device__ __forceinline__ unsigned short f2bf(float f) {
  union { float f; uint32_t u; } c; c.f = f;
  uint32_t r = (c.u + 0x7FFFu + ((c.u >> 16) & 1u)) >> 16;
  return (unsigned short)r;
}
static __device__ __forceinline__ float bf2f(unsigned short u) {
  union { uint32_t u; float f; } c; c.u = (uint32_t)u << 16; return c.f;
}

// ---------------- persistent pipelined encoder (rank-1 layer0 + GEMM layer1) ----------------
__global__ __launch_bounds__(256) void enc_kernel(
    int M, int tiles, int tpb, const float* __restrict__ x,
    const float* __restrict__ W0v, const float* __restrict__ b0,
    const unsigned short* __restrict__ wt1, const float* __restrict__ b1,
    unsigned short* __restrict__ outB) {
  __shared__ __align__(16) unsigned short h_lds[64 * 128];
  __shared__ float s_x[64];
  const int tid = threadIdx.x, wave = tid >> 6, lane = tid & 63;
  const int wm = wave >> 1, wn = wave & 1, l15 = lane & 15, l4 = lane >> 4;
  int t0 = blockIdx.x * tpb, t1 = t0 + tpb; if (t1 > tiles) t1 = tiles;
  if (t0 >= tiles) return;

  bf16x8 b1f[4][4];
  float w0c[4], b0c[4], bb1[4];
  #pragma unroll
  for (int nt = 0; nt < 4; ++nt) {
    int n = wn * 64 + nt * 16 + l15;
    w0c[nt] = W0v[n]; b0c[nt] = b0[n]; bb1[nt] = b1[n];
    #pragma unroll
    for (int ks = 0; ks < 4; ++ks)
      b1f[ks][nt] = *(const bf16x8*)(wt1 + (size_t)n * 128 + ks * 32 + l4 * 8);
  }

  int row0 = t0 * 64;
  int xi = row0 + (tid & 63); if (xi > M - 1) xi = M - 1;
  float xr = x[xi];

  for (int t = t0; t < t1; ++t) {
    int nt_ = (t + 1 < t1) ? (t + 1) : t;
    int nrow0 = nt_ * 64;
    if (wave == 0) s_x[lane] = xr;
    BARRIER_LGKM();
    #pragma unroll
    for (int mt = 0; mt < 2; ++mt)
      #pragma unroll
      for (int r = 0; r < 4; ++r) {
        int rowb = wm * 32 + mt * 16 + l4 * 4 + r;
        float xv = s_x[rowb];
        #pragma unroll
        for (int nt = 0; nt < 4; ++nt) {
          int colb = wn * 64 + nt * 16 + l15;
          float v = fmaxf(xv * w0c[nt] + b0c[nt], 0.0f);
          h_lds[rowb * 128 + (colb ^ ((rowb & 7) << 3))] = f2bf(v);
        }
      }
    // prefetch next x
    int nxi = nrow0 + (tid & 63); if (nxi > M - 1) nxi = M - 1;
    xr = x[nxi];
    BARRIER_LGKM();
    f32x4 acc[2][4] = {};
    #pragma unroll
    for (int ks = 0; ks < 4; ++ks) {
      bf16x8 a1[2];
      #pragma unroll
      for (int mt = 0; mt < 2; ++mt) {
        int rowb = wm * 32 + mt * 16 + l15;
        a1[mt] = *(const bf16x8*)&h_lds[rowb * 128 + ((ks * 32 + l4 * 8) ^ ((rowb & 7) << 3))];
      }
      #pragma unroll
      for (int mt = 0; mt < 2; ++mt)
        #pragma unroll
        for (int nt = 0; nt < 4; ++nt)
          acc[mt][nt] = MFMA16(a1[mt], b1f[ks][nt], acc[mt][nt]);
    }
    #pragma unroll
    for (int mt = 0; mt < 2; ++mt)
      #pragma unroll
      for (int nt = 0; nt < 4; ++nt) {
        int colb = wn * 64 + nt * 16 + l15;
        #pragma unroll
        for (int r = 0; r < 4; ++r) {
          int rowb = wm * 32 + mt * 16 + l4 * 4 + r;
          int gm = row0 + rowb;
          if (gm < M) outB[(size_t)gm * 128 + colb] = f2bf(acc[mt][nt][r] + bb1[nt]);
        }
      }
    row0 = nrow0;
  }
}

// ---------------- persistent pipelined edge block (K=384, gathered ln via LDS) ----------------
// r6 body, but __launch_bounds__(256, 3): cap VGPR at 170 so 3 blocks/CU fit
// (LDS 48KB x 3 = 144 <= 160KB). Compiler chooses which weight frags stay
// persistent vs L1-rematerialized under the cap (r9's manual split failed at
// 208 VGPR -> no occupancy gain; forcing the threshold is the point).
__global__ __launch_bounds__(256, 3) void edge_kernel(
    int E, int tiles, int tpb, unsigned short* __restrict__ le,
    const unsigned short* __restrict__ ln,
    const int* __restrict__ row_p, const int* __restrict__ col_p,
    const unsigned short* __restrict__ wt0,  // [128][384]
    const float* __restrict__ b0,
    const unsigned short* __restrict__ wt1, const float* __restrict__ b1) {
  __shared__ __align__(16) unsigned short lnr_lds[64 * 128];
  __shared__ __align__(16) unsigned short lnc_lds[64 * 128];
  __shared__ __align__(16) unsigned short h_lds[64 * 128];
  const int tid = threadIdx.x, wave = tid >> 6, lane = tid & 63;
  const int wm = wave >> 1, wn = wave & 1, l15 = lane & 15, l4 = lane >> 4;
  int t0 = blockIdx.x * tpb, t1 = t0 + tpb; if (t1 > tiles) t1 = tiles;
  if (t0 >= tiles) return;

  // persistent weights (compiler balances under the 170-VGPR cap)
  bf16x8 bR[4][4], bC[4][4], bE[4][4], b1f[4][4];
  float bb0[4], bb1[4];
  #pragma unroll
  for (int nt = 0; nt < 4; ++nt) {
    int n = wn * 64 + nt * 16 + l15;
    bb0[nt] = b0[n]; bb1[nt] = b1[n];
    #pragma unroll
    for (int ks = 0; ks < 4; ++ks) {
      int k = ks * 32 + l4 * 8;
      bR[ks][nt]  = *(const bf16x8*)(wt0 + (size_t)n * 384 + k);
      bC[ks][nt]  = *(const bf16x8*)(wt0 + (size_t)n * 384 + 128 + k);
      bE[ks][nt]  = *(const bf16x8*)(wt0 + (size_t)n * 384 + 256 + k);
      b1f[ks][nt] = *(const bf16x8*)(wt1 + (size_t)n * 128 + k);
    }
  }

  // prologue: prefetch tile t0 (idx -> gathers -> le frags)
  int row0 = t0 * 64;
  int il = row0 + 16 * wave + l15; if (il > E - 1) il = E - 1;
  int myrow = row_p[il], mycol = col_p[il];
  bf16x8 gR[4], gC[4], a[2][4];
  #pragma unroll
  for (int i = 0; i < 4; ++i) {
    int rl = 4 * i + l4;
    int rr = __shfl(myrow, rl, 64);
    int cc = __shfl(mycol, rl, 64);
    gR[i] = *(const bf16x8*)(ln + (size_t)rr * 128 + l15 * 8);
    gC[i] = *(const bf16x8*)(ln + (size_t)cc * 128 + l15 * 8);
  }
  #pragma unroll
  for (int mt = 0; mt < 2; ++mt) {
    int gm = row0 + wm * 32 + mt * 16 + l15; if (gm > E - 1) gm = E - 1;
    #pragma unroll
    for (int ks = 0; ks < 4; ++ks)
      a[mt][ks] = *(const bf16x8*)(le + (size_t)gm * 128 + ks * 32 + l4 * 8);
  }

  for (int t = t0; t < t1; ++t) {
    int tn = (t + 1 < t1) ? (t + 1) : t;
    int nrow0 = tn * 64;
    // [0] idx prefetch for t+1 (L2-resident, arrives before [5])
    int nil = nrow0 + 16 * wave + l15; if (nil > E - 1) nil = E - 1;
    int nmyrow = row_p[nil], nmycol = col_p[nil];
    // [1] ds_write staged gathers (XOR-swizzled chunk)
    #pragma unroll
    for (int i = 0; i < 4; ++i) {
      int rowl = 16 * wave + 4 * i + l4;
      int off = rowl * 128 + ((l15 ^ (rowl & 7)) << 3);
      *(bf16x8*)&lnr_lds[off] = gR[i];
      *(bf16x8*)&lnc_lds[off] = gC[i];
    }
    // [2] layer0, le slice (register A, overlaps ds_write latency)
    f32x4 acc[2][4] = {};
    #pragma unroll
    for (int ks = 0; ks < 4; ++ks)
      #pragma unroll
      for (int mt = 0; mt < 2; ++mt)
        #pragma unroll
        for (int nt = 0; nt < 4; ++nt)
          acc[mt][nt] = MFMA16(a[mt][ks], bE[ks][nt], acc[mt][nt]);
    // [3] barrier A: lnr/lnc visible
    BARRIER_LGKM();
    // [4] layer0, row/col slices from LDS (T5: favor MFMA-entering wave)
    __builtin_amdgcn_s_setprio(1);
    #pragma unroll
    for (int ks = 0; ks < 4; ++ks) {
      bf16x8 ar[2], ac[2];
      #pragma unroll
      for (int mt = 0; mt < 2; ++mt) {
        int rowb = wm * 32 + mt * 16 + l15;
        int off = rowb * 128 + (((ks * 4 + l4) ^ (rowb & 7)) << 3);
        ar[mt] = *(const bf16x8*)&lnr_lds[off];
        ac[mt] = *(const bf16x8*)&lnc_lds[off];
      }
      #pragma unroll
      for (int mt = 0; mt < 2; ++mt)
        #pragma unroll
        for (int nt = 0; nt < 4; ++nt) {
          acc[mt][nt] = MFMA16(ar[mt], bR[ks][nt], acc[mt][nt]);
          acc[mt][nt] = MFMA16(ac[mt], bC[ks][nt], acc[mt][nt]);
        }
    }
    __builtin_amdgcn_s_setprio(0);
    // [5] issue t+1 prefetch: gathers + le frags (hidden under [6]-[9] + next [1]-[2])
    #pragma unroll
    for (int i = 0; i < 4; ++i) {
      int rl = 4 * i + l4;
      int rr = __shfl(nmyrow, rl, 64);
      int cc = __shfl(nmycol, rl, 64);
      gR[i] = *(const bf16x8*)(ln + (size_t)rr * 128 + l15 * 8);
      gC[i] = *(const bf16x8*)(ln + (size_t)cc * 128 + l15 * 8);
    }
    #pragma unroll
    for (int mt = 0; mt < 2; ++mt) {
      int gm = nrow0 + wm * 32 + mt * 16 + l15; if (gm > E - 1) gm = E - 1;
      #pragma unroll
      for (int ks = 0; ks < 4; ++ks)
        a[mt][ks] = *(const bf16x8*)(le + (size_t)gm * 128 + ks * 32 + l4 * 8);
    }
    // [6] h = relu(acc + b0) -> h_lds
    #pragma unroll
    for (int mt = 0; mt < 2; ++mt)
      #pragma unroll
      for (int nt = 0; nt < 4; ++nt) {
        int colb = wn * 64 + nt * 16 + l15;
        #pragma unroll
        for (int r = 0; r < 4; ++r) {
          int rowb = wm * 32 + mt * 16 + l4 * 4 + r;
          h_lds[rowb * 128 + (colb ^ ((rowb & 7) << 3))] =
              f2bf(fmaxf(acc[mt][nt][r] + bb0[nt], 0.0f));
        }
      }
    // [7] barrier B
    BARRIER_LGKM();
    // [8] layer1
    f32x4 acc1[2][4] = {};
    #pragma unroll
    for (int ks = 0; ks < 4; ++ks) {
      bf16x8 a1[2];
      #pragma unroll
      for (int mt = 0; mt < 2; ++mt) {
        int rowb = wm * 32 + mt * 16 + l15;
        a1[mt] = *(const bf16x8*)&h_lds[rowb * 128 + ((ks * 32 + l4 * 8) ^ ((rowb & 7) << 3))];
      }
      #pragma unroll
      for (int mt = 0; mt < 2; ++mt)
        #pragma unroll
        for (int nt = 0; nt < 4; ++nt)
          acc1[mt][nt] = MFMA16(a1[mt], b1f[ks][nt], acc1[mt][nt]);
    }
    // [9] store new le
    #pragma unroll
    for (int mt = 0; mt < 2; ++mt)
      #pragma unroll
      for (int nt = 0; nt < 4; ++nt) {
        int colb = wn * 64 + nt * 16 + l15;
        #pragma unroll
        for (int r = 0; r < 4; ++r) {
          int rowb = wm * 32 + mt * 16 + l4 * 4 + r;
          int gm = row0 + rowb;
          if (gm < E) le[(size_t)gm * 128 + colb] = f2bf(acc1[mt][nt][r] + bb1[nt]);
        }
      }
    row0 = nrow0;
  }
}

// ---------------- node block (one-shot; N is small) ----------------
__global__ __launch_bounds__(256) void node_kernel(
    int M, unsigned short* __restrict__ ln, const unsigned short* __restrict__ aggb,
    const unsigned short* __restrict__ wt0, const float* __restrict__ b0,
    const unsigned short* __restrict__ wt1, const float* __restrict__ b1) {
  __shared__ __align__(16) unsigned short h_lds[64 * 128];
  const int tid = threadIdx.x, wave = tid >> 6, lane = tid & 63;
  const int wm = wave >> 1, wn = wave & 1, l15 = lane & 15, l4 = lane >> 4;
  const int row0 = blockIdx.x * 64;

  bf16x8 a[2][8];
  #pragma unroll
  for (int mt = 0; mt < 2; ++mt) {
    int gm = row0 + wm * 32 + mt * 16 + l15; if (gm > M - 1) gm = M - 1;
    #pragma unroll
    for (int ks = 0; ks < 4; ++ks) {
      a[mt][ks]     = *(const bf16x8*)(ln   + (size_t)gm * 128 + ks * 32 + l4 * 8);
      a[mt][4 + ks] = *(const bf16x8*)(aggb + (size_t)gm * 128 + ks * 32 + l4 * 8);
    }
  }
  bf16x8 b0f[8][4];
  #pragma unroll
  for (int nt = 0; nt < 4; ++nt) {
    int n = wn * 64 + nt * 16 + l15;
    #pragma unroll
    for (int ks = 0; ks < 8; ++ks)
      b0f[ks][nt] = *(const bf16x8*)(wt0 + (size_t)n * 256 + ks * 32 + l4 * 8);
  }
  f32x4 acc[2][4] = {};
  #pragma unroll
  for (int ks = 0; ks < 8; ++ks)
    #pragma unroll
    for (int mt = 0; mt < 2; ++mt)
      #pragma unroll
      for (int nt = 0; nt < 4; ++nt)
        acc[mt][nt] = MFMA16(a[mt][ks], b0f[ks][nt], acc[mt][nt]);

  bf16x8 b1f[4][4];
  #pragma unroll
  for (int nt = 0; nt < 4; ++nt) {
    int n = wn * 64 + nt * 16 + l15;
    #pragma unroll
    for (int ks = 0; ks < 4; ++ks)
      b1f[ks][nt] = *(const bf16x8*)(wt1 + (size_t)n * 128 + ks * 32 + l4 * 8);
  }
  #pragma unroll
  for (int mt = 0; mt < 2; ++mt)
    #pragma unroll
    for (int nt = 0; nt < 4; ++nt) {
      int colb = wn * 64 + nt * 16 + l15;
      float bb = b0[colb];
      #pragma unroll
      for (int r = 0; r < 4; ++r) {
        int rowb = wm * 32 + mt * 16 + l4 * 4 + r;
        h_lds[rowb * 128 + (colb ^ ((rowb & 7) << 3))] = f2bf(fmaxf(acc[mt][nt][r] + bb, 0.0f));
      }
    }
  __syncthreads();
  f32x4 acc1[2][4] = {};
  #pragma unroll
  for (int ks = 0; ks < 4; ++ks) {
    bf16x8 a1[2];
    #pragma unroll
    for (int mt = 0; mt < 2; ++mt) {
      int rowb = wm * 32 + mt * 16 + l15;
      a1[mt] = *(const bf16x8*)&h_lds[rowb * 128 + ((ks * 32 + l4 * 8) ^ ((rowb & 7) << 3))];
    }
    #pragma unroll
    for (int mt = 0; mt < 2; ++mt)
      #pragma unroll
      for (int nt = 0; nt < 4; ++nt)
        acc1[mt][nt] = MFMA16(a1[mt], b1f[ks][nt], acc1[mt][nt]);
  }
  #pragma unroll
  for (int mt = 0; mt < 2; ++mt)
    #pragma unroll
    for (int nt = 0; nt < 4; ++nt) {
      int colb = wn * 64 + nt * 16 + l15;
      float bb = b1[colb];
      #pragma unroll
      for (int r = 0; r < 4; ++r) {
        int rowb = wm * 32 + mt * 16 + l4 * 4 + r;
        int gm = row0 + rowb;
        if (gm < M) ln[(size_t)gm * 128 + colb] = f2bf(acc1[mt][nt][r] + bb);
      }
    }
}

// ---------------- persistent pipelined decoder ----------------
__global__ __launch_bounds__(256) void dec_kernel(
    int E, int tiles, int tpb, const unsigned short* __restrict__ le,
    const int* __restrict__ row_p, const int* __restrict__ col_p,
    const int* __restrict__ eid, const float* __restrict__ ea_p,
    const unsigned short* __restrict__ wt0, const float* __restrict__ b0,
    const float* __restrict__ decW1, const float* __restrict__ decB1,
    float* __restrict__ dout) {
  __shared__ float s_dec[2][2][64];
  const int tid = threadIdx.x, wave = tid >> 6, lane = tid & 63;
  const int wm = wave >> 1, wn = wave & 1, l15 = lane & 15, l4 = lane >> 4;
  int t0 = blockIdx.x * tpb, t1 = t0 + tpb; if (t1 > tiles) t1 = tiles;
  if (t0 >= tiles) return;

  bf16x8 b0f[4][4];
  float w1c[4], b0c[4];
  #pragma unroll
  for (int nt = 0; nt < 4; ++nt) {
    int n = wn * 64 + nt * 16 + l15;
    w1c[nt] = decW1[n]; b0c[nt] = b0[n];
    #pragma unroll
    for (int ks = 0; ks < 4; ++ks)
      b0f[ks][nt] = *(const bf16x8*)(wt0 + (size_t)n * 128 + ks * 32 + l4 * 8);
  }
  float db1 = decB1[0];

  int row0 = t0 * 64;
  bf16x8 a[2][4];
  #pragma unroll
  for (int mt = 0; mt < 2; ++mt) {
    int gm = row0 + wm * 32 + mt * 16 + l15; if (gm > E - 1) gm = E - 1;
    #pragma unroll
    for (int ks = 0; ks < 4; ++ks)
      a[mt][ks] = *(const bf16x8*)(le + (size_t)gm * 128 + ks * 32 + l4 * 8);
  }
  int e0 = row0 + (tid & 63); if (e0 > E - 1) e0 = E - 1;
  int rr = row_p[e0], cc = col_p[e0], ee = eid[e0];
  float eav = ea_p[e0];
  int p = 0;

  for (int t = t0; t < t1; ++t) {
    int tn = (t + 1 < t1) ? (t + 1) : t;
    int nrow0 = tn * 64;
    f32x4 acc[2][4] = {};
    #pragma unroll
    for (int ks = 0; ks < 4; ++ks)
      #pragma unroll
      for (int mt = 0; mt < 2; ++mt)
        #pragma unroll
        for (int nt = 0; nt < 4; ++nt)
          acc[mt][nt] = MFMA16(a[mt][ks], b0f[ks][nt], acc[mt][nt]);
    // prefetch t+1
    #pragma unroll
    for (int mt = 0; mt < 2; ++mt) {
      int gm = nrow0 + wm * 32 + mt * 16 + l15; if (gm > E - 1) gm = E - 1;
      #pragma unroll
      for (int ks = 0; ks < 4; ++ks)
        a[mt][ks] = *(const bf16x8*)(le + (size_t)gm * 128 + ks * 32 + l4 * 8);
    }
    int ne0 = nrow0 + (tid & 63); if (ne0 > E - 1) ne0 = E - 1;
    int nrr = row_p[ne0], ncc = col_p[ne0], nee = eid[ne0];
    float neav = ea_p[ne0];

    float part[2][4] = {};
    #pragma unroll
    for (int mt = 0; mt < 2; ++mt)
      #pragma unroll
      for (int nt = 0; nt < 4; ++nt)
        #pragma unroll
        for (int r = 0; r < 4; ++r)
          part[mt][r] += fmaxf(acc[mt][nt][r] + b0c[nt], 0.0f) * w1c[nt];
    #pragma unroll
    for (int mt = 0; mt < 2; ++mt)
      #pragma unroll
      for (int r = 0; r < 4; ++r) {
        float v = part[mt][r];
        #pragma unroll
        for (int off = 1; off < 16; off <<= 1) v += __shfl_xor(v, off, 64);
        if (l15 == 0) s_dec[p][wn][wm * 32 + mt * 16 + l4 * 4 + r] = v;
      }
    BARRIER_LGKM();
    if (tid < 64) {
      int gm = row0 + tid;
      if (gm < E) {
        float v = s_dec[p][0][tid] + s_dec[p][1][tid] + db1;
        if (rr == cc) v = 0.5f * sqrtf(eav);
        dout[ee] = v;
      }
    }
    rr = nrr; cc = ncc; ee = nee; eav = neav;
    row0 = nrow0; p ^= 1;
  }
}

// ---------------- graph prep ----------------
struct TransDesc { const float* src[16]; unsigned short* dst[16]; int K[16]; };

__global__ void trans_kernel(TransDesc td) {
  int m = blockIdx.y;
  int k = blockIdx.x;
  if (k >= td.K[m]) return;
  int n = threadIdx.x;  // 128
  td.dst[m][(size_t)n * td.K[m] + k] = f2bf(td.src[m][(size_t)k * 128 + n]);
}

__global__ void deg_kernel(const int* __restrict__ row, int E, int* cnt) {
  int i = blockIdx.x * blockDim.x + threadIdx.x;
  if (i < E) atomicAdd(&cnt[row[i]], 1);
}

__global__ void invcnt_kernel(const int* __restrict__ cnt, int N, float* inv) {
  int i = blockIdx.x * blockDim.x + threadIdx.x;
  if (i < N) { int c = cnt[i]; inv[i] = 1.0f / (float)(c > 1 ? c : 1); }
}

__global__ __launch_bounds__(1024) void scan_kernel(const int* __restrict__ cnt, int N,
                                                    int* __restrict__ offs, int* __restrict__ cursor) {
  __shared__ int lds[1024];
  __shared__ int carry;
  if (threadIdx.x == 0) carry = 0;
  __syncthreads();
  for (int base = 0; base < N; base += 1024) {
    int i = base + (int)threadIdx.x;
    int v = (i < N) ? cnt[i] : 0;
    lds[threadIdx.x] = v;
    __syncthreads();
    #pragma unroll
    for (int off = 1; off < 1024; off <<= 1) {
      int t = (threadIdx.x >= (unsigned)off) ? lds[threadIdx.x - off] : 0;
      __syncthreads();
      lds[threadIdx.x] += t;
      __syncthreads();
    }
    int excl = lds[threadIdx.x] - v + carry;
    if (i < N) { offs[i] = excl; cursor[i] = excl; }
    __syncthreads();
    if (threadIdx.x == 1023) carry += lds[1023];
    __syncthreads();
  }
}

__global__ void scatter_kernel(const int* __restrict__ row, int E,
                               int* __restrict__ cursor, int* __restrict__ eid) {
  int i = blockIdx.x * blockDim.x + threadIdx.x;
  if (i < E) {
    int r = row[i];
    int pos = atomicAdd(&cursor[r], 1);
    eid[pos] = i;
  }
}

__global__ void permute_kernel(const int* __restrict__ eid,
                               const int* __restrict__ row, const int* __restrict__ col,
                               const float* __restrict__ ea, int E,
                               int* __restrict__ row_p, int* __restrict__ col_p,
                               float* __restrict__ ea_p) {
  int i = blockIdx.x * blockDim.x + threadIdx.x;
  if (i < E) {
    int e = eid[i];
    row_p[i] = row[e];
    col_p[i] = col[e];
    ea_p[i]  = ea[e];
  }
}

__global__ __launch_bounds__(256) void agg_kernel(const unsigned short* __restrict__ le,
                                                  const int* __restrict__ offs,
                                                  const int* __restrict__ cnt,
                                                  const float* __restrict__ inv,
                                                  unsigned short* __restrict__ aggb, int N) {
  int wave = threadIdx.x >> 6, lane = threadIdx.x & 63;
  int n = blockIdx.x * 4 + wave;
  if (n >= N) return;
  int beg = offs[n], d = cnt[n];
  const unsigned short* base = le + (size_t)beg * 128 + lane * 2;
  float sx0 = 0, sy0 = 0, sx1 = 0, sy1 = 0, sx2 = 0, sy2 = 0, sx3 = 0, sy3 = 0;
  int j = 0;
  for (; j + 3 < d; j += 4) {
    ushort2 v0 = *(const ushort2*)(base + (size_t)j * 128);
    ushort2 v1 = *(const ushort2*)(base + (size_t)(j + 1) * 128);
    ushort2 v2 = *(const ushort2*)(base + (size_t)(j + 2) * 128);
    ushort2 v3 = *(const ushort2*)(base + (size_t)(j + 3) * 128);
    sx0 += bf2f(v0.x); sy0 += bf2f(v0.y);
    sx1 += bf2f(v1.x); sy1 += bf2f(v1.y);
    sx2 += bf2f(v2.x); sy2 += bf2f(v2.y);
    sx3 += bf2f(v3.x); sy3 += bf2f(v3.y);
  }
  for (; j < d; ++j) {
    ushort2 v0 = *(const ushort2*)(base + (size_t)j * 128);
    sx0 += bf2f(v0.x); sy0 += bf2f(v0.y);
  }
  float iv = inv[n];
  ushort2 o;
  o.x = f2bf((sx0 + sx1 + sx2 + sx3) * iv);
  o.y = f2bf((sy0 + sy1 + sy2 + sy3) * iv);
  *(ushort2*)(aggb + (size_t)n * 128 + lane * 2) = o;
}

extern "C" void kernel_launch(void* const* d_in, const int* in_sizes, int n_in,
                              void* d_out, int out_size, void* d_ws, size_t ws_size,
                              hipStream_t stream) {
  const float* x         = (const float*)d_in[0];
  const float* edge_attr = (const float*)d_in[1];
  const int*   eidx      = (const int*)  d_in[2];
  const float* encn_W0 = (const float*)d_in[3];
  const float* encn_b0 = (const float*)d_in[4];
  const float* encn_W1 = (const float*)d_in[5];
  const float* encn_b1 = (const float*)d_in[6];
  const float* ence_W0 = (const float*)d_in[7];
  const float* ence_b0 = (const float*)d_in[8];
  const float* ence_W1 = (const float*)d_in[9];
  const float* ence_b1 = (const float*)d_in[10];
  const float* dec_W0  = (const float*)d_in[11];
  const float* dec_b0  = (const float*)d_in[12];
  const float* dec_W1  = (const float*)d_in[13];
  const float* dec_b1  = (const float*)d_in[14];
  const float* eW0 = (const float*)d_in[15];
  const float* eb0 = (const float*)d_in[16];
  const float* eW1 = (const float*)d_in[17];
  const float* eb1 = (const float*)d_in[18];
  const float* nW0 = (const float*)d_in[19];
  const float* nb0 = (const float*)d_in[20];
  const float* nW1 = (const float*)d_in[21];
  const float* nb1 = (const float*)d_in[22];

  const int N = in_sizes[0];
  const int E = in_sizes[1];
  const int* rowI = eidx;
  const int* colI = eidx + E;

  char* w = (char*)d_ws;
  auto take = [&](size_t bytes) -> char* {
    char* p = w; w += (bytes + 255) & ~(size_t)255; return p;
  };
  unsigned short* ln   = (unsigned short*)take((size_t)N * 128 * 2);
  unsigned short* le   = (unsigned short*)take((size_t)E * 128 * 2);  // CSR order
  unsigned short* aggb = (unsigned short*)take((size_t)N * 128 * 2);
  int*            cnt  = (int*)take((size_t)N * 4);
  float*          inv  = (float*)take((size_t)N * 4);
  int*            offs = (int*)take((size_t)N * 4);
  int*            curs = (int*)take((size_t)N * 4);
  int*            eidArr = (int*)take((size_t)E * 4);
  int*            row_p  = (int*)take((size_t)E * 4);
  int*            col_p  = (int*)take((size_t)E * 4);
  float*          ea_p   = (float*)take((size_t)E * 4);
  unsigned short* wt_encn1 = (unsigned short*)take(128 * 128 * 2);
  unsigned short* wt_ence1 = (unsigned short*)take(128 * 128 * 2);
  unsigned short* wt_dec0  = (unsigned short*)take(128 * 128 * 2);
  unsigned short *wt_e0[3], *wt_e1[3], *wt_n0[2], *wt_n1[2];
  for (int s = 0; s < 3; ++s) wt_e0[s] = (unsigned short*)take(384 * 128 * 2);
  for (int s = 0; s < 3; ++s) wt_e1[s] = (unsigned short*)take(128 * 128 * 2);
  for (int s = 0; s < 2; ++s) wt_n0[s] = (unsigned short*)take(256 * 128 * 2);
  for (int s = 0; s < 2; ++s) wt_n1[s] = (unsigned short*)take(128 * 128 * 2);

  TransDesc td{};
  int mi = 0;
  auto add = [&](const float* s, unsigned short* d, int K) {
    td.src[mi] = s; td.dst[mi] = d; td.K[mi] = K; ++mi;
  };
  add(encn_W1, wt_encn1, 128);
  add(ence_W1, wt_ence1, 128);
  add(dec_W0,  wt_dec0,  128);
  for (int s = 0; s < 3; ++s) add(eW0 + (size_t)s * 384 * 128, wt_e0[s], 384);
  for (int s = 0; s < 3; ++s) add(eW1 + (size_t)s * 128 * 128, wt_e1[s], 128);
  for (int s = 0; s < 2; ++s) add(nW0 + (size_t)s * 256 * 128, wt_n0[s], 256);
  for (int s = 0; s < 2; ++s) add(nW1 + (size_t)s * 128 * 128, wt_n1[s], 128);

  hipMemsetAsync(cnt, 0, (size_t)N * 4, stream);
  trans_kernel<<<dim3(384, mi), 128, 0, stream>>>(td);
  deg_kernel<<<(E + 255) / 256, 256, 0, stream>>>(rowI, E, cnt);
  invcnt_kernel<<<(N + 255) / 256, 256, 0, stream>>>(cnt, N, inv);
  scan_kernel<<<1, 1024, 0, stream>>>(cnt, N, offs, curs);
  scatter_kernel<<<(E + 255) / 256, 256, 0, stream>>>(rowI, E, curs, eidArr);
  permute_kernel<<<(E + 255) / 256, 256, 0, stream>>>(eidArr, rowI, colI, edge_attr, E,
                                                      row_p, col_p, ea_p);

  const int tilesN = (N + 63) / 64;
  const int tilesE = (E + 63) / 64;
  const int TPB_ENC = 4, TPB_EDGE = 7, TPB_DEC = 4;
  const int G_ENC_E = (tilesE + TPB_ENC - 1) / TPB_ENC;
  const int G_EDGE  = (tilesE + TPB_EDGE - 1) / TPB_EDGE;  // 715 <= 768 slots @3/CU
  const int G_DEC   = (tilesE + TPB_DEC - 1) / TPB_DEC;

  enc_kernel<<<tilesN, 256, 0, stream>>>(N, tilesN, 1, x, encn_W0, encn_b0,
                                         wt_encn1, encn_b1, ln);
  enc_kernel<<<G_ENC_E, 256, 0, stream>>>(E, tilesE, TPB_ENC, ea_p, ence_W0, ence_b0,
                                          wt_ence1, ence_b1, le);

  for (int s = 0; s < 3; ++s) {
    edge_kernel<<<G_EDGE, 256, 0, stream>>>(E, tilesE, TPB_EDGE, le, ln, row_p, col_p,
                                            wt_e0[s], eb0 + s * 128,
                                            wt_e1[s], eb1 + s * 128);
    if (s < 2) {
      // agg3/node3 are dead code: decoder consumes only le3
      agg_kernel<<<(N + 3) / 4, 256, 0, stream>>>(le, offs, cnt, inv, aggb, N);
      node_kernel<<<(N + 63) / 64, 256, 0, stream>>>(N, ln, aggb, wt_n0[s], nb0 + s * 128,
                                                     wt_n1[s], nb1 + s * 128);
    }
  }
  dec_kernel<<<G_DEC, 256, 0, stream>>>(E, tilesE, TPB_DEC, le, row_p, col_p, eidArr, ea_p,
                                        wt_dec0, dec_b0, dec_W1, dec_b1,
                                        (float*)d_out);
}

// Round 12
// 508.793 us; speedup vs baseline: 2.6907x; 2.6907x over previous
//
#include <hip/hip_runtime.h>
#include <hip/hip_bf16.h>
#include <stdint.h>

typedef __attribute__((ext_vector_type(8))) short bf16x8;
typedef __attribute__((ext_vector_type(4))) float f32x4;

#define MFMA16(a, b, c) __builtin_amdgcn_mfma_f32_16x16x32_bf16((a), (b), (c), 0, 0, 0)

// raw barrier: drain own LDS ops, then s_barrier. NO vmcnt drain -> global
// prefetch loads stay in flight across the barrier.
#define BARRIER_LGKM() do { \
  asm volatile("s_waitcnt lgkmcnt(0)" ::: "memory"); \
  __builtin_amdgcn_sched_barrier(0); \
  __builtin_amdgcn_s_barrier(); \
  __builtin_amdgcn_sched_barrier(0); } while (0)

static __device__ __forceinline__ unsigned short f2bf(float f) {
  union { float f; uint32_t u; } c; c.f = f;
  uint32_t r = (c.u + 0x7FFFu + ((c.u >> 16) & 1u)) >> 16;
  return (unsigned short)r;
}
static __device__ __forceinline__ float bf2f(unsigned short u) {
  union { uint32_t u; float f; } c; c.u = (uint32_t)u << 16; return c.f;
}

// ---------------- persistent pipelined encoder (rank-1 layer0 + GEMM layer1) ----------------
__global__ __launch_bounds__(256) void enc_kernel(
    int M, int tiles, int tpb, const float* __restrict__ x,
    const float* __restrict__ W0v, const float* __restrict__ b0,
    const unsigned short* __restrict__ wt1, const float* __restrict__ b1,
    unsigned short* __restrict__ outB) {
  __shared__ __align__(16) unsigned short h_lds[64 * 128];
  __shared__ float s_x[64];
  const int tid = threadIdx.x, wave = tid >> 6, lane = tid & 63;
  const int wm = wave >> 1, wn = wave & 1, l15 = lane & 15, l4 = lane >> 4;
  int t0 = blockIdx.x * tpb, t1 = t0 + tpb; if (t1 > tiles) t1 = tiles;
  if (t0 >= tiles) return;

  bf16x8 b1f[4][4];
  float w0c[4], b0c[4], bb1[4];
  #pragma unroll
  for (int nt = 0; nt < 4; ++nt) {
    int n = wn * 64 + nt * 16 + l15;
    w0c[nt] = W0v[n]; b0c[nt] = b0[n]; bb1[nt] = b1[n];
    #pragma unroll
    for (int ks = 0; ks < 4; ++ks)
      b1f[ks][nt] = *(const bf16x8*)(wt1 + (size_t)n * 128 + ks * 32 + l4 * 8);
  }

  int row0 = t0 * 64;
  int xi = row0 + (tid & 63); if (xi > M - 1) xi = M - 1;
  float xr = x[xi];

  for (int t = t0; t < t1; ++t) {
    int nt_ = (t + 1 < t1) ? (t + 1) : t;
    int nrow0 = nt_ * 64;
    if (wave == 0) s_x[lane] = xr;
    BARRIER_LGKM();
    #pragma unroll
    for (int mt = 0; mt < 2; ++mt)
      #pragma unroll
      for (int r = 0; r < 4; ++r) {
        int rowb = wm * 32 + mt * 16 + l4 * 4 + r;
        float xv = s_x[rowb];
        #pragma unroll
        for (int nt = 0; nt < 4; ++nt) {
          int colb = wn * 64 + nt * 16 + l15;
          float v = fmaxf(xv * w0c[nt] + b0c[nt], 0.0f);
          h_lds[rowb * 128 + (colb ^ ((rowb & 7) << 3))] = f2bf(v);
        }
      }
    // prefetch next x
    int nxi = nrow0 + (tid & 63); if (nxi > M - 1) nxi = M - 1;
    xr = x[nxi];
    BARRIER_LGKM();
    f32x4 acc[2][4] = {};
    #pragma unroll
    for (int ks = 0; ks < 4; ++ks) {
      bf16x8 a1[2];
      #pragma unroll
      for (int mt = 0; mt < 2; ++mt) {
        int rowb = wm * 32 + mt * 16 + l15;
        a1[mt] = *(const bf16x8*)&h_lds[rowb * 128 + ((ks * 32 + l4 * 8) ^ ((rowb & 7) << 3))];
      }
      #pragma unroll
      for (int mt = 0; mt < 2; ++mt)
        #pragma unroll
        for (int nt = 0; nt < 4; ++nt)
          acc[mt][nt] = MFMA16(a1[mt], b1f[ks][nt], acc[mt][nt]);
    }
    #pragma unroll
    for (int mt = 0; mt < 2; ++mt)
      #pragma unroll
      for (int nt = 0; nt < 4; ++nt) {
        int colb = wn * 64 + nt * 16 + l15;
        #pragma unroll
        for (int r = 0; r < 4; ++r) {
          int rowb = wm * 32 + mt * 16 + l4 * 4 + r;
          int gm = row0 + rowb;
          if (gm < M) outB[(size_t)gm * 128 + colb] = f2bf(acc[mt][nt][r] + bb1[nt]);
        }
      }
    row0 = nrow0;
  }
}

// ---------------- persistent pipelined edge block (K=384, gathered ln via LDS) ----------------
// r6/r10 body (known-good ~106us config): all 4 weight arrays persistent,
// compiler-balanced at ~224 VGPR, 2 blocks/CU. NO occupancy cap (r11's (256,3)
// cap forced VGPR 224->84 -> catastrophic scratch spill, 380us/dispatch).
// Grid shaping does the occupancy work instead: grid 500 <= 512 slots -> no tail.
__global__ __launch_bounds__(256) void edge_kernel(
    int E, int tiles, int tpb, unsigned short* __restrict__ le,
    const unsigned short* __restrict__ ln,
    const int* __restrict__ row_p, const int* __restrict__ col_p,
    const unsigned short* __restrict__ wt0,  // [128][384]
    const float* __restrict__ b0,
    const unsigned short* __restrict__ wt1, const float* __restrict__ b1) {
  __shared__ __align__(16) unsigned short lnr_lds[64 * 128];
  __shared__ __align__(16) unsigned short lnc_lds[64 * 128];
  __shared__ __align__(16) unsigned short h_lds[64 * 128];
  const int tid = threadIdx.x, wave = tid >> 6, lane = tid & 63;
  const int wm = wave >> 1, wn = wave & 1, l15 = lane & 15, l4 = lane >> 4;
  int t0 = blockIdx.x * tpb, t1 = t0 + tpb; if (t1 > tiles) t1 = tiles;
  if (t0 >= tiles) return;

  // persistent weights: W0 row/col/edge slices + W1 (all L2-hot)
  bf16x8 bR[4][4], bC[4][4], bE[4][4], b1f[4][4];
  float bb0[4], bb1[4];
  #pragma unroll
  for (int nt = 0; nt < 4; ++nt) {
    int n = wn * 64 + nt * 16 + l15;
    bb0[nt] = b0[n]; bb1[nt] = b1[n];
    #pragma unroll
    for (int ks = 0; ks < 4; ++ks) {
      int k = ks * 32 + l4 * 8;
      bR[ks][nt]  = *(const bf16x8*)(wt0 + (size_t)n * 384 + k);
      bC[ks][nt]  = *(const bf16x8*)(wt0 + (size_t)n * 384 + 128 + k);
      bE[ks][nt]  = *(const bf16x8*)(wt0 + (size_t)n * 384 + 256 + k);
      b1f[ks][nt] = *(const bf16x8*)(wt1 + (size_t)n * 128 + k);
    }
  }

  // prologue: prefetch tile t0 (idx -> gathers -> le frags)
  int row0 = t0 * 64;
  int il = row0 + 16 * wave + l15; if (il > E - 1) il = E - 1;
  int myrow = row_p[il], mycol = col_p[il];
  bf16x8 gR[4], gC[4], a[2][4];
  #pragma unroll
  for (int i = 0; i < 4; ++i) {
    int rl = 4 * i + l4;
    int rr = __shfl(myrow, rl, 64);
    int cc = __shfl(mycol, rl, 64);
    gR[i] = *(const bf16x8*)(ln + (size_t)rr * 128 + l15 * 8);
    gC[i] = *(const bf16x8*)(ln + (size_t)cc * 128 + l15 * 8);
  }
  #pragma unroll
  for (int mt = 0; mt < 2; ++mt) {
    int gm = row0 + wm * 32 + mt * 16 + l15; if (gm > E - 1) gm = E - 1;
    #pragma unroll
    for (int ks = 0; ks < 4; ++ks)
      a[mt][ks] = *(const bf16x8*)(le + (size_t)gm * 128 + ks * 32 + l4 * 8);
  }

  for (int t = t0; t < t1; ++t) {
    int tn = (t + 1 < t1) ? (t + 1) : t;
    int nrow0 = tn * 64;
    // [0] idx prefetch for t+1 (L2-resident, arrives before [5])
    int nil = nrow0 + 16 * wave + l15; if (nil > E - 1) nil = E - 1;
    int nmyrow = row_p[nil], nmycol = col_p[nil];
    // [1] ds_write staged gathers (XOR-swizzled chunk)
    #pragma unroll
    for (int i = 0; i < 4; ++i) {
      int rowl = 16 * wave + 4 * i + l4;
      int off = rowl * 128 + ((l15 ^ (rowl & 7)) << 3);
      *(bf16x8*)&lnr_lds[off] = gR[i];
      *(bf16x8*)&lnc_lds[off] = gC[i];
    }
    // [2] layer0, le slice (register A, overlaps ds_write latency)
    f32x4 acc[2][4] = {};
    #pragma unroll
    for (int ks = 0; ks < 4; ++ks)
      #pragma unroll
      for (int mt = 0; mt < 2; ++mt)
        #pragma unroll
        for (int nt = 0; nt < 4; ++nt)
          acc[mt][nt] = MFMA16(a[mt][ks], bE[ks][nt], acc[mt][nt]);
    // [3] barrier A: lnr/lnc visible
    BARRIER_LGKM();
    // [4] layer0, row/col slices from LDS (T5: favor MFMA-entering wave)
    __builtin_amdgcn_s_setprio(1);
    #pragma unroll
    for (int ks = 0; ks < 4; ++ks) {
      bf16x8 ar[2], ac[2];
      #pragma unroll
      for (int mt = 0; mt < 2; ++mt) {
        int rowb = wm * 32 + mt * 16 + l15;
        int off = rowb * 128 + (((ks * 4 + l4) ^ (rowb & 7)) << 3);
        ar[mt] = *(const bf16x8*)&lnr_lds[off];
        ac[mt] = *(const bf16x8*)&lnc_lds[off];
      }
      #pragma unroll
      for (int mt = 0; mt < 2; ++mt)
        #pragma unroll
        for (int nt = 0; nt < 4; ++nt) {
          acc[mt][nt] = MFMA16(ar[mt], bR[ks][nt], acc[mt][nt]);
          acc[mt][nt] = MFMA16(ac[mt], bC[ks][nt], acc[mt][nt]);
        }
    }
    __builtin_amdgcn_s_setprio(0);
    // [5] issue t+1 prefetch: gathers + le frags (hidden under [6]-[9] + next [1]-[2])
    #pragma unroll
    for (int i = 0; i < 4; ++i) {
      int rl = 4 * i + l4;
      int rr = __shfl(nmyrow, rl, 64);
      int cc = __shfl(nmycol, rl, 64);
      gR[i] = *(const bf16x8*)(ln + (size_t)rr * 128 + l15 * 8);
      gC[i] = *(const bf16x8*)(ln + (size_t)cc * 128 + l15 * 8);
    }
    #pragma unroll
    for (int mt = 0; mt < 2; ++mt) {
      int gm = nrow0 + wm * 32 + mt * 16 + l15; if (gm > E - 1) gm = E - 1;
      #pragma unroll
      for (int ks = 0; ks < 4; ++ks)
        a[mt][ks] = *(const bf16x8*)(le + (size_t)gm * 128 + ks * 32 + l4 * 8);
    }
    // [6] h = relu(acc + b0) -> h_lds
    #pragma unroll
    for (int mt = 0; mt < 2; ++mt)
      #pragma unroll
      for (int nt = 0; nt < 4; ++nt) {
        int colb = wn * 64 + nt * 16 + l15;
        #pragma unroll
        for (int r = 0; r < 4; ++r) {
          int rowb = wm * 32 + mt * 16 + l4 * 4 + r;
          h_lds[rowb * 128 + (colb ^ ((rowb & 7) << 3))] =
              f2bf(fmaxf(acc[mt][nt][r] + bb0[nt], 0.0f));
        }
      }
    // [7] barrier B
    BARRIER_LGKM();
    // [8] layer1
    f32x4 acc1[2][4] = {};
    #pragma unroll
    for (int ks = 0; ks < 4; ++ks) {
      bf16x8 a1[2];
      #pragma unroll
      for (int mt = 0; mt < 2; ++mt) {
        int rowb = wm * 32 + mt * 16 + l15;
        a1[mt] = *(const bf16x8*)&h_lds[rowb * 128 + ((ks * 32 + l4 * 8) ^ ((rowb & 7) << 3))];
      }
      #pragma unroll
      for (int mt = 0; mt < 2; ++mt)
        #pragma unroll
        for (int nt = 0; nt < 4; ++nt)
          acc1[mt][nt] = MFMA16(a1[mt], b1f[ks][nt], acc1[mt][nt]);
    }
    // [9] store new le
    #pragma unroll
    for (int mt = 0; mt < 2; ++mt)
      #pragma unroll
      for (int nt = 0; nt < 4; ++nt) {
        int colb = wn * 64 + nt * 16 + l15;
        #pragma unroll
        for (int r = 0; r < 4; ++r) {
          int rowb = wm * 32 + mt * 16 + l4 * 4 + r;
          int gm = row0 + rowb;
          if (gm < E) le[(size_t)gm * 128 + colb] = f2bf(acc1[mt][nt][r] + bb1[nt]);
        }
      }
    row0 = nrow0;
  }
}

// ---------------- node block (one-shot; N is small) ----------------
__global__ __launch_bounds__(256) void node_kernel(
    int M, unsigned short* __restrict__ ln, const unsigned short* __restrict__ aggb,
    const unsigned short* __restrict__ wt0, const float* __restrict__ b0,
    const unsigned short* __restrict__ wt1, const float* __restrict__ b1) {
  __shared__ __align__(16) unsigned short h_lds[64 * 128];
  const int tid = threadIdx.x, wave = tid >> 6, lane = tid & 63;
  const int wm = wave >> 1, wn = wave & 1, l15 = lane & 15, l4 = lane >> 4;
  const int row0 = blockIdx.x * 64;

  bf16x8 a[2][8];
  #pragma unroll
  for (int mt = 0; mt < 2; ++mt) {
    int gm = row0 + wm * 32 + mt * 16 + l15; if (gm > M - 1) gm = M - 1;
    #pragma unroll
    for (int ks = 0; ks < 4; ++ks) {
      a[mt][ks]     = *(const bf16x8*)(ln   + (size_t)gm * 128 + ks * 32 + l4 * 8);
      a[mt][4 + ks] = *(const bf16x8*)(aggb + (size_t)gm * 128 + ks * 32 + l4 * 8);
    }
  }
  bf16x8 b0f[8][4];
  #pragma unroll
  for (int nt = 0; nt < 4; ++nt) {
    int n = wn * 64 + nt * 16 + l15;
    #pragma unroll
    for (int ks = 0; ks < 8; ++ks)
      b0f[ks][nt] = *(const bf16x8*)(wt0 + (size_t)n * 256 + ks * 32 + l4 * 8);
  }
  f32x4 acc[2][4] = {};
  #pragma unroll
  for (int ks = 0; ks < 8; ++ks)
    #pragma unroll
    for (int mt = 0; mt < 2; ++mt)
      #pragma unroll
      for (int nt = 0; nt < 4; ++nt)
        acc[mt][nt] = MFMA16(a[mt][ks], b0f[ks][nt], acc[mt][nt]);

  bf16x8 b1f[4][4];
  #pragma unroll
  for (int nt = 0; nt < 4; ++nt) {
    int n = wn * 64 + nt * 16 + l15;
    #pragma unroll
    for (int ks = 0; ks < 4; ++ks)
      b1f[ks][nt] = *(const bf16x8*)(wt1 + (size_t)n * 128 + ks * 32 + l4 * 8);
  }
  #pragma unroll
  for (int mt = 0; mt < 2; ++mt)
    #pragma unroll
    for (int nt = 0; nt < 4; ++nt) {
      int colb = wn * 64 + nt * 16 + l15;
      float bb = b0[colb];
      #pragma unroll
      for (int r = 0; r < 4; ++r) {
        int rowb = wm * 32 + mt * 16 + l4 * 4 + r;
        h_lds[rowb * 128 + (colb ^ ((rowb & 7) << 3))] = f2bf(fmaxf(acc[mt][nt][r] + bb, 0.0f));
      }
    }
  __syncthreads();
  f32x4 acc1[2][4] = {};
  #pragma unroll
  for (int ks = 0; ks < 4; ++ks) {
    bf16x8 a1[2];
    #pragma unroll
    for (int mt = 0; mt < 2; ++mt) {
      int rowb = wm * 32 + mt * 16 + l15;
      a1[mt] = *(const bf16x8*)&h_lds[rowb * 128 + ((ks * 32 + l4 * 8) ^ ((rowb & 7) << 3))];
    }
    #pragma unroll
    for (int mt = 0; mt < 2; ++mt)
      #pragma unroll
      for (int nt = 0; nt < 4; ++nt)
        acc1[mt][nt] = MFMA16(a1[mt], b1f[ks][nt], acc1[mt][nt]);
  }
  #pragma unroll
  for (int mt = 0; mt < 2; ++mt)
    #pragma unroll
    for (int nt = 0; nt < 4; ++nt) {
      int colb = wn * 64 + nt * 16 + l15;
      float bb = b1[colb];
      #pragma unroll
      for (int r = 0; r < 4; ++r) {
        int rowb = wm * 32 + mt * 16 + l4 * 4 + r;
        int gm = row0 + rowb;
        if (gm < M) ln[(size_t)gm * 128 + colb] = f2bf(acc1[mt][nt][r] + bb);
      }
    }
}

// ---------------- persistent pipelined decoder ----------------
__global__ __launch_bounds__(256) void dec_kernel(
    int E, int tiles, int tpb, const unsigned short* __restrict__ le,
    const int* __restrict__ row_p, const int* __restrict__ col_p,
    const int* __restrict__ eid, const float* __restrict__ ea_p,
    const unsigned short* __restrict__ wt0, const float* __restrict__ b0,
    const float* __restrict__ decW1, const float* __restrict__ decB1,
    float* __restrict__ dout) {
  __shared__ float s_dec[2][2][64];
  const int tid = threadIdx.x, wave = tid >> 6, lane = tid & 63;
  const int wm = wave >> 1, wn = wave & 1, l15 = lane & 15, l4 = lane >> 4;
  int t0 = blockIdx.x * tpb, t1 = t0 + tpb; if (t1 > tiles) t1 = tiles;
  if (t0 >= tiles) return;

  bf16x8 b0f[4][4];
  float w1c[4], b0c[4];
  #pragma unroll
  for (int nt = 0; nt < 4; ++nt) {
    int n = wn * 64 + nt * 16 + l15;
    w1c[nt] = decW1[n]; b0c[nt] = b0[n];
    #pragma unroll
    for (int ks = 0; ks < 4; ++ks)
      b0f[ks][nt] = *(const bf16x8*)(wt0 + (size_t)n * 128 + ks * 32 + l4 * 8);
  }
  float db1 = decB1[0];

  int row0 = t0 * 64;
  bf16x8 a[2][4];
  #pragma unroll
  for (int mt = 0; mt < 2; ++mt) {
    int gm = row0 + wm * 32 + mt * 16 + l15; if (gm > E - 1) gm = E - 1;
    #pragma unroll
    for (int ks = 0; ks < 4; ++ks)
      a[mt][ks] = *(const bf16x8*)(le + (size_t)gm * 128 + ks * 32 + l4 * 8);
  }
  int e0 = row0 + (tid & 63); if (e0 > E - 1) e0 = E - 1;
  int rr = row_p[e0], cc = col_p[e0], ee = eid[e0];
  float eav = ea_p[e0];
  int p = 0;

  for (int t = t0; t < t1; ++t) {
    int tn = (t + 1 < t1) ? (t + 1) : t;
    int nrow0 = tn * 64;
    f32x4 acc[2][4] = {};
    #pragma unroll
    for (int ks = 0; ks < 4; ++ks)
      #pragma unroll
      for (int mt = 0; mt < 2; ++mt)
        #pragma unroll
        for (int nt = 0; nt < 4; ++nt)
          acc[mt][nt] = MFMA16(a[mt][ks], b0f[ks][nt], acc[mt][nt]);
    // prefetch t+1
    #pragma unroll
    for (int mt = 0; mt < 2; ++mt) {
      int gm = nrow0 + wm * 32 + mt * 16 + l15; if (gm > E - 1) gm = E - 1;
      #pragma unroll
      for (int ks = 0; ks < 4; ++ks)
        a[mt][ks] = *(const bf16x8*)(le + (size_t)gm * 128 + ks * 32 + l4 * 8);
    }
    int ne0 = nrow0 + (tid & 63); if (ne0 > E - 1) ne0 = E - 1;
    int nrr = row_p[ne0], ncc = col_p[ne0], nee = eid[ne0];
    float neav = ea_p[ne0];

    float part[2][4] = {};
    #pragma unroll
    for (int mt = 0; mt < 2; ++mt)
      #pragma unroll
      for (int nt = 0; nt < 4; ++nt)
        #pragma unroll
        for (int r = 0; r < 4; ++r)
          part[mt][r] += fmaxf(acc[mt][nt][r] + b0c[nt], 0.0f) * w1c[nt];
    #pragma unroll
    for (int mt = 0; mt < 2; ++mt)
      #pragma unroll
      for (int r = 0; r < 4; ++r) {
        float v = part[mt][r];
        #pragma unroll
        for (int off = 1; off < 16; off <<= 1) v += __shfl_xor(v, off, 64);
        if (l15 == 0) s_dec[p][wn][wm * 32 + mt * 16 + l4 * 4 + r] = v;
      }
    BARRIER_LGKM();
    if (tid < 64) {
      int gm = row0 + tid;
      if (gm < E) {
        float v = s_dec[p][0][tid] + s_dec[p][1][tid] + db1;
        if (rr == cc) v = 0.5f * sqrtf(eav);
        dout[ee] = v;
      }
    }
    rr = nrr; cc = ncc; ee = nee; eav = neav;
    row0 = nrow0; p ^= 1;
  }
}

// ---------------- graph prep ----------------
struct TransDesc { const float* src[16]; unsigned short* dst[16]; int K[16]; };

__global__ void trans_kernel(TransDesc td) {
  int m = blockIdx.y;
  int k = blockIdx.x;
  if (k >= td.K[m]) return;
  int n = threadIdx.x;  // 128
  td.dst[m][(size_t)n * td.K[m] + k] = f2bf(td.src[m][(size_t)k * 128 + n]);
}

__global__ void deg_kernel(const int* __restrict__ row, int E, int* cnt) {
  int i = blockIdx.x * blockDim.x + threadIdx.x;
  if (i < E) atomicAdd(&cnt[row[i]], 1);
}

__global__ void invcnt_kernel(const int* __restrict__ cnt, int N, float* inv) {
  int i = blockIdx.x * blockDim.x + threadIdx.x;
  if (i < N) { int c = cnt[i]; inv[i] = 1.0f / (float)(c > 1 ? c : 1); }
}

__global__ __launch_bounds__(1024) void scan_kernel(const int* __restrict__ cnt, int N,
                                                    int* __restrict__ offs, int* __restrict__ cursor) {
  __shared__ int lds[1024];
  __shared__ int carry;
  if (threadIdx.x == 0) carry = 0;
  __syncthreads();
  for (int base = 0; base < N; base += 1024) {
    int i = base + (int)threadIdx.x;
    int v = (i < N) ? cnt[i] : 0;
    lds[threadIdx.x] = v;
    __syncthreads();
    #pragma unroll
    for (int off = 1; off < 1024; off <<= 1) {
      int t = (threadIdx.x >= (unsigned)off) ? lds[threadIdx.x - off] : 0;
      __syncthreads();
      lds[threadIdx.x] += t;
      __syncthreads();
    }
    int excl = lds[threadIdx.x] - v + carry;
    if (i < N) { offs[i] = excl; cursor[i] = excl; }
    __syncthreads();
    if (threadIdx.x == 1023) carry += lds[1023];
    __syncthreads();
  }
}

__global__ void scatter_kernel(const int* __restrict__ row, int E,
                               int* __restrict__ cursor, int* __restrict__ eid) {
  int i = blockIdx.x * blockDim.x + threadIdx.x;
  if (i < E) {
    int r = row[i];
    int pos = atomicAdd(&cursor[r], 1);
    eid[pos] = i;
  }
}

__global__ void permute_kernel(const int* __restrict__ eid,
                               const int* __restrict__ row, const int* __restrict__ col,
                               const float* __restrict__ ea, int E,
                               int* __restrict__ row_p, int* __restrict__ col_p,
                               float* __restrict__ ea_p) {
  int i = blockIdx.x * blockDim.x + threadIdx.x;
  if (i < E) {
    int e = eid[i];
    row_p[i] = row[e];
    col_p[i] = col[e];
    ea_p[i]  = ea[e];
  }
}

__global__ __launch_bounds__(256) void agg_kernel(const unsigned short* __restrict__ le,
                                                  const int* __restrict__ offs,
                                                  const int* __restrict__ cnt,
                                                  const float* __restrict__ inv,
                                                  unsigned short* __restrict__ aggb, int N) {
  int wave = threadIdx.x >> 6, lane = threadIdx.x & 63;
  int n = blockIdx.x * 4 + wave;
  if (n >= N) return;
  int beg = offs[n], d = cnt[n];
  const unsigned short* base = le + (size_t)beg * 128 + lane * 2;
  float sx0 = 0, sy0 = 0, sx1 = 0, sy1 = 0, sx2 = 0, sy2 = 0, sx3 = 0, sy3 = 0;
  int j = 0;
  for (; j + 3 < d; j += 4) {
    ushort2 v0 = *(const ushort2*)(base + (size_t)j * 128);
    ushort2 v1 = *(const ushort2*)(base + (size_t)(j + 1) * 128);
    ushort2 v2 = *(const ushort2*)(base + (size_t)(j + 2) * 128);
    ushort2 v3 = *(const ushort2*)(base + (size_t)(j + 3) * 128);
    sx0 += bf2f(v0.x); sy0 += bf2f(v0.y);
    sx1 += bf2f(v1.x); sy1 += bf2f(v1.y);
    sx2 += bf2f(v2.x); sy2 += bf2f(v2.y);
    sx3 += bf2f(v3.x); sy3 += bf2f(v3.y);
  }
  for (; j < d; ++j) {
    ushort2 v0 = *(const ushort2*)(base + (size_t)j * 128);
    sx0 += bf2f(v0.x); sy0 += bf2f(v0.y);
  }
  float iv = inv[n];
  ushort2 o;
  o.x = f2bf((sx0 + sx1 + sx2 + sx3) * iv);
  o.y = f2bf((sy0 + sy1 + sy2 + sy3) * iv);
  *(ushort2*)(aggb + (size_t)n * 128 + lane * 2) = o;
}

extern "C" void kernel_launch(void* const* d_in, const int* in_sizes, int n_in,
                              void* d_out, int out_size, void* d_ws, size_t ws_size,
                              hipStream_t stream) {
  const float* x         = (const float*)d_in[0];
  const float* edge_attr = (const float*)d_in[1];
  const int*   eidx      = (const int*)  d_in[2];
  const float* encn_W0 = (const float*)d_in[3];
  const float* encn_b0 = (const float*)d_in[4];
  const float* encn_W1 = (const float*)d_in[5];
  const float* encn_b1 = (const float*)d_in[6];
  const float* ence_W0 = (const float*)d_in[7];
  const float* ence_b0 = (const float*)d_in[8];
  const float* ence_W1 = (const float*)d_in[9];
  const float* ence_b1 = (const float*)d_in[10];
  const float* dec_W0  = (const float*)d_in[11];
  const float* dec_b0  = (const float*)d_in[12];
  const float* dec_W1  = (const float*)d_in[13];
  const float* dec_b1  = (const float*)d_in[14];
  const float* eW0 = (const float*)d_in[15];
  const float* eb0 = (const float*)d_in[16];
  const float* eW1 = (const float*)d_in[17];
  const float* eb1 = (const float*)d_in[18];
  const float* nW0 = (const float*)d_in[19];
  const float* nb0 = (const float*)d_in[20];
  const float* nW1 = (const float*)d_in[21];
  const float* nb1 = (const float*)d_in[22];

  const int N = in_sizes[0];
  const int E = in_sizes[1];
  const int* rowI = eidx;
  const int* colI = eidx + E;

  char* w = (char*)d_ws;
  auto take = [&](size_t bytes) -> char* {
    char* p = w; w += (bytes + 255) & ~(size_t)255; return p;
  };
  unsigned short* ln   = (unsigned short*)take((size_t)N * 128 * 2);
  unsigned short* le   = (unsigned short*)take((size_t)E * 128 * 2);  // CSR order
  unsigned short* aggb = (unsigned short*)take((size_t)N * 128 * 2);
  int*            cnt  = (int*)take((size_t)N * 4);
  float*          inv  = (float*)take((size_t)N * 4);
  int*            offs = (int*)take((size_t)N * 4);
  int*            curs = (int*)take((size_t)N * 4);
  int*            eidArr = (int*)take((size_t)E * 4);
  int*            row_p  = (int*)take((size_t)E * 4);
  int*            col_p  = (int*)take((size_t)E * 4);
  float*          ea_p   = (float*)take((size_t)E * 4);
  unsigned short* wt_encn1 = (unsigned short*)take(128 * 128 * 2);
  unsigned short* wt_ence1 = (unsigned short*)take(128 * 128 * 2);
  unsigned short* wt_dec0  = (unsigned short*)take(128 * 128 * 2);
  unsigned short *wt_e0[3], *wt_e1[3], *wt_n0[2], *wt_n1[2];
  for (int s = 0; s < 3; ++s) wt_e0[s] = (unsigned short*)take(384 * 128 * 2);
  for (int s = 0; s < 3; ++s) wt_e1[s] = (unsigned short*)take(128 * 128 * 2);
  for (int s = 0; s < 2; ++s) wt_n0[s] = (unsigned short*)take(256 * 128 * 2);
  for (int s = 0; s < 2; ++s) wt_n1[s] = (unsigned short*)take(128 * 128 * 2);

  TransDesc td{};
  int mi = 0;
  auto add = [&](const float* s, unsigned short* d, int K) {
    td.src[mi] = s; td.dst[mi] = d; td.K[mi] = K; ++mi;
  };
  add(encn_W1, wt_encn1, 128);
  add(ence_W1, wt_ence1, 128);
  add(dec_W0,  wt_dec0,  128);
  for (int s = 0; s < 3; ++s) add(eW0 + (size_t)s * 384 * 128, wt_e0[s], 384);
  for (int s = 0; s < 3; ++s) add(eW1 + (size_t)s * 128 * 128, wt_e1[s], 128);
  for (int s = 0; s < 2; ++s) add(nW0 + (size_t)s * 256 * 128, wt_n0[s], 256);
  for (int s = 0; s < 2; ++s) add(nW1 + (size_t)s * 128 * 128, wt_n1[s], 128);

  hipMemsetAsync(cnt, 0, (size_t)N * 4, stream);
  trans_kernel<<<dim3(384, mi), 128, 0, stream>>>(td);
  deg_kernel<<<(E + 255) / 256, 256, 0, stream>>>(rowI, E, cnt);
  invcnt_kernel<<<(N + 255) / 256, 256, 0, stream>>>(cnt, N, inv);
  scan_kernel<<<1, 1024, 0, stream>>>(cnt, N, offs, curs);
  scatter_kernel<<<(E + 255) / 256, 256, 0, stream>>>(rowI, E, curs, eidArr);
  permute_kernel<<<(E + 255) / 256, 256, 0, stream>>>(eidArr, rowI, colI, edge_attr, E,
                                                      row_p, col_p, ea_p);

  const int tilesN = (N + 63) / 64;
  const int tilesE = (E + 63) / 64;
  // no-tail grids, capacity-derived:
  //  edge: VGPR 224 -> 2 blocks/CU -> 512 slots; TPB=10 -> grid 500 <= 512
  //  dec:  VGPR ~150 -> >=3 blocks/CU -> >=768 slots; TPB=7 -> grid 715 <= 768
  //  enc:  VGPR ~100 -> >=5 blocks/CU -> >=1280 slots; TPB=4 -> grid 1250 <= 1280
  const int TPB_ENC = 4, TPB_EDGE = 10, TPB_DEC = 7;
  const int G_ENC_E = (tilesE + TPB_ENC - 1) / TPB_ENC;
  const int G_EDGE  = (tilesE + TPB_EDGE - 1) / TPB_EDGE;
  const int G_DEC   = (tilesE + TPB_DEC - 1) / TPB_DEC;

  enc_kernel<<<tilesN, 256, 0, stream>>>(N, tilesN, 1, x, encn_W0, encn_b0,
                                         wt_encn1, encn_b1, ln);
  enc_kernel<<<G_ENC_E, 256, 0, stream>>>(E, tilesE, TPB_ENC, ea_p, ence_W0, ence_b0,
                                          wt_ence1, ence_b1, le);

  for (int s = 0; s < 3; ++s) {
    edge_kernel<<<G_EDGE, 256, 0, stream>>>(E, tilesE, TPB_EDGE, le, ln, row_p, col_p,
                                            wt_e0[s], eb0 + s * 128,
                                            wt_e1[s], eb1 + s * 128);
    if (s < 2) {
      // agg3/node3 are dead code: decoder consumes only le3
      agg_kernel<<<(N + 3) / 4, 256, 0, stream>>>(le, offs, cnt, inv, aggb, N);
      node_kernel<<<(N + 63) / 64, 256, 0, stream>>>(N, ln, aggb, wt_n0[s], nb0 + s * 128,
                                                     wt_n1[s], nb1 + s * 128);
    }
  }
  dec_kernel<<<G_DEC, 256, 0, stream>>>(E, tilesE, TPB_DEC, le, row_p, col_p, eidArr, ea_p,
                                        wt_dec0, dec_b0, dec_W1, dec_b1,
                                        (float*)d_out);
}